// Round 1
// 808.340 us; speedup vs baseline: 4.2566x; 4.2566x over previous
//
#include <hip/hip_runtime.h>

// Problem constants (from reference): B=4, C=64, H=384, W=768
#define Bc  4
#define Cc  64
#define Hc  384
#define Wc  768
#define HWc (Hc * Wc)                 // 294912
#define FEATc ((long)Bc * Cc * HWc)   // 75497472

// ===========================================================================
// FAST PATH (transposed accumulator, channel-contiguous atomics)
// ===========================================================================

// K1-T: scatter splat with (B, HW, C) accumulator layout.
// Block = 256 threads (4 waves) handles 64 source pixels.
//   - threads 0..63 compute idx/w for the 64 pixels (+1 wacc atomic each)
//   - all threads cooperatively load the 64ch x 64pix fmap tile, transposed
//     into LDS (pad 65 -> conflict-free both directions)
//   - each wave splats 16 pixels: lane = channel, 64 consecutive-float
//     atomics per pixel => 2 cache lines instead of 65 scattered lines.
__global__ __launch_bounds__(256) void scatter_t_k(
    const float* __restrict__ fmap,    // (B, C, HW)
    const float* __restrict__ flow,    // (B, 2, HW)
    const float* __restrict__ depth,   // (B, 1, HW)
    float* __restrict__ facc_t,        // (B, HW, C) accumulator
    float* __restrict__ wacc)          // (B, HW) weight accumulator
{
    __shared__ float tile[64][65];     // [pixel][channel], padded
    __shared__ int   idx_s[64];
    __shared__ float w_s[64];

    const int t    = threadIdx.x;
    const int lane = t & 63;
    const int wv   = t >> 6;
    const int p0   = blockIdx.x * 64;
    const int b    = blockIdx.y;

    if (t < 64) {
        const int p = p0 + t;
        const float fx = flow[((long)b * 2 + 0) * HWc + p];
        const float fy = flow[((long)b * 2 + 1) * HWc + p];
        const float tx = (float)(p % Wc) + fx;
        const float ty = (float)(p / Wc) + fy;
        int   id = -1;
        float w  = 0.f;
        if (tx >= 0.f && tx < (float)(Wc - 1) && ty >= 0.f && ty < (float)(Hc - 1)) {
            id = (int)ty * Wc + (int)tx;   // trunc == floor (coords >= 0)
            w  = __expf(-depth[(long)b * HWc + p]);
            unsafeAtomicAdd(wacc + (long)b * HWc + id, w);
        }
        idx_s[t] = id;
        w_s[t]   = w;
    }

    // Coalesced fmap tile load: each wave reads 64 consecutive pixels of one
    // channel (256B burst); store transposed into LDS.
    {
        const float* src = fmap + (long)b * Cc * HWc + p0 + lane;
#pragma unroll
        for (int i = 0; i < 16; ++i) {
            const int c = i * 4 + wv;
            tile[lane][c] = src[(long)c * HWc];
        }
    }
    __syncthreads();

    // Wave-wide coalesced atomics: 64 lanes -> 64 consecutive floats.
#pragma unroll
    for (int j = 0; j < 16; ++j) {
        const int q  = wv * 16 + j;
        const int id = idx_s[q];
        if (id >= 0) {
            unsafeAtomicAdd(facc_t + ((long)b * HWc + id) * 64 + lane,
                            tile[q][lane] * w_s[q]);
        }
    }
}

// K2-T: normalize + transpose one batch: (HW, C)/w -> (C, HW).
// Both global sides fully coalesced via a padded LDS tile.
__global__ __launch_bounds__(256) void norm_t_k(
    const float* __restrict__ src_t,   // (HW, C) batch accumulator
    const float* __restrict__ wb,      // (HW) batch weights
    float* __restrict__ dst)           // (C, HW) final batch features
{
    __shared__ float tile[64][65];     // [channel][pixel], padded
    __shared__ float w_s[64];

    const int t    = threadIdx.x;
    const int lane = t & 63;
    const int wv   = t >> 6;
    const int p0   = blockIdx.x * 64;

    if (t < 64) {
        const float w = wb[p0 + t];
        w_s[t] = (w > 0.f) ? (1.f / w) : 1.f;
    }
    __syncthreads();

    // Read (pixel, channel) coalesced (lane = channel), scale, store [c][pix].
#pragma unroll
    for (int i = 0; i < 16; ++i) {
        const int pix = i * 4 + wv;
        tile[lane][pix] = src_t[(long)(p0 + pix) * 64 + lane] * w_s[pix];
    }
    __syncthreads();

    // Write (channel, pixel) coalesced (lane = pixel).
#pragma unroll
    for (int i = 0; i < 16; ++i) {
        const int c = i * 4 + wv;
        dst[(long)c * HWc + p0 + lane] = tile[c][lane];
    }
}

// K3: weights -> 0/1 mask, in place (after normalization).
__global__ __launch_bounds__(256) void mask_k(float* __restrict__ wacc)
{
    const int i = blockIdx.x * 256 + threadIdx.x;   // float4 index
    float4 w = *(float4*)(wacc + (long)i * 4);
    w.x = (w.x > 0.f) ? 1.f : 0.f;
    w.y = (w.y > 0.f) ? 1.f : 0.f;
    w.z = (w.z > 0.f) ? 1.f : 0.f;
    w.w = (w.w > 0.f) ? 1.f : 0.f;
    *(float4*)(wacc + (long)i * 4) = w;
}

// ===========================================================================
// FALLBACK PATH (previous version, verbatim) — used only if d_ws is too small
// ===========================================================================

__global__ __launch_bounds__(256) void scatter_k(
    const float* __restrict__ fmap,
    const float* __restrict__ flow,
    const float* __restrict__ depth,
    float* __restrict__ facc,
    float* __restrict__ wacc)
{
    const int p = blockIdx.x * 256 + threadIdx.x;
    const int b = blockIdx.y;

    const float fx = flow[((long)b * 2 + 0) * HWc + p];
    const float fy = flow[((long)b * 2 + 1) * HWc + p];
    const int x = p % Wc;
    const int y = p / Wc;
    const float tx = (float)x + fx;
    const float ty = (float)y + fy;

    if (!(tx >= 0.f && tx < (float)(Wc - 1) && ty >= 0.f && ty < (float)(Hc - 1)))
        return;

    const int idx = (int)ty * Wc + (int)tx;
    const float w = __expf(-depth[(long)b * HWc + p]);

    atomicAdd(wacc + (long)b * HWc + idx, w);

    const float* src = fmap + (long)b * Cc * HWc + p;
    float*       dst = facc + (long)b * Cc * HWc + idx;
#pragma unroll
    for (int c = 0; c < Cc; ++c) {
        atomicAdd(dst + (long)c * HWc, src[(long)c * HWc] * w);
    }
}

__global__ __launch_bounds__(256) void norm_k(
    float* __restrict__ facc,
    const float* __restrict__ wacc)
{
    const int bpb = (Cc * HWc) / 1024;
    const int b   = blockIdx.x / bpb;
    const int blk = blockIdx.x % bpb;
    const int e   = blk * 1024 + threadIdx.x * 4;
    const int p   = e % HWc;

    const float4 w4 = *(const float4*)(wacc + (long)b * HWc + p);
    float4 f = *(float4*)(facc + (long)b * (Cc * HWc) + e);
    if (w4.x > 0.f) f.x /= w4.x;
    if (w4.y > 0.f) f.y /= w4.y;
    if (w4.z > 0.f) f.z /= w4.z;
    if (w4.w > 0.f) f.w /= w4.w;
    *(float4*)(facc + (long)b * (Cc * HWc) + e) = f;
}

// ===========================================================================

extern "C" void kernel_launch(void* const* d_in, const int* in_sizes, int n_in,
                              void* d_out, int out_size, void* d_ws, size_t ws_size,
                              hipStream_t stream)
{
    const float* fmap  = (const float*)d_in[0];   // (B,C,H,W)
    const float* flow  = (const float*)d_in[1];   // (B,2,H,W)
    const float* depth = (const float*)d_in[2];   // (B,1,H,W)

    float* out  = (float*)d_out;
    float* facc = out;            // final features: B*C*HW floats
    float* wacc = out + FEATc;    // weight accumulator -> becomes mask

    const size_t featBytes  = (size_t)FEATc * sizeof(float);        // ~302 MB
    const size_t batchBytes = (size_t)Cc * HWc * sizeof(float);     // ~75.5 MB

    if (ws_size >= featBytes) {
        // ---- Path A: transposed accumulator lives in workspace ----
        float* facc_t = (float*)d_ws;
        hipMemsetAsync(d_ws, 0, featBytes, stream);
        hipMemsetAsync(wacc, 0, (size_t)Bc * HWc * sizeof(float), stream);

        dim3 g1(HWc / 64, Bc);
        scatter_t_k<<<g1, 256, 0, stream>>>(fmap, flow, depth, facc_t, wacc);

        for (int b = 0; b < Bc; ++b) {
            norm_t_k<<<HWc / 64, 256, 0, stream>>>(
                facc_t + (long)b * HWc * 64,
                wacc   + (long)b * HWc,
                facc   + (long)b * Cc * HWc);
        }
        mask_k<<<(Bc * HWc) / 1024, 256, 0, stream>>>(wacc);
    } else if (ws_size >= batchBytes) {
        // ---- Path B: transposed accumulator in d_out, per-batch staging ----
        float* facc_t = out;   // (B, HW, C) occupying the facc region
        hipMemsetAsync(d_out, 0, (size_t)out_size * sizeof(float), stream);

        dim3 g1(HWc / 64, Bc);
        scatter_t_k<<<g1, 256, 0, stream>>>(fmap, flow, depth, facc_t, wacc);

        for (int b = 0; b < Bc; ++b) {
            hipMemcpyAsync(d_ws, facc_t + (long)b * HWc * 64, batchBytes,
                           hipMemcpyDeviceToDevice, stream);
            norm_t_k<<<HWc / 64, 256, 0, stream>>>(
                (const float*)d_ws,
                wacc + (long)b * HWc,
                facc + (long)b * Cc * HWc);
        }
        mask_k<<<(Bc * HWc) / 1024, 256, 0, stream>>>(wacc);
    } else {
        // ---- Path C: previous verified version ----
        hipMemsetAsync(d_out, 0, (size_t)out_size * sizeof(float), stream);

        dim3 g1(HWc / 256, Bc);
        scatter_k<<<g1, 256, 0, stream>>>(fmap, flow, depth, facc, wacc);

        const int norm_blocks = (int)(FEATc / 1024);
        norm_k<<<norm_blocks, 256, 0, stream>>>(facc, wacc);

        const int mask_blocks = (Bc * HWc) / 1024;
        mask_k<<<mask_blocks, 256, 0, stream>>>(wacc);
    }
}

// Round 2
// 793.047 us; speedup vs baseline: 4.3386x; 1.0193x over previous
//
#include <hip/hip_runtime.h>

// Problem constants (from reference): B=4, C=64, H=384, W=768
#define Bc  4
#define Cc  64
#define Hc  384
#define Wc  768
#define HWc (Hc * Wc)                 // 294912
#define FEATc ((long)Bc * Cc * HWc)   // 75497472

typedef float v4f __attribute__((ext_vector_type(4)));

// ===========================================================================
// FAST PATH (transposed accumulator, channel-contiguous atomics)
// ===========================================================================

// K1-T: scatter splat with (B, HW, C) accumulator layout.
// Block = 256 threads (4 waves) handles 64 source pixels.
//   - threads 0..63 compute idx/w for the 64 pixels (+1 wacc atomic each)
//   - all threads cooperatively load the 64ch x 64pix fmap tile, transposed
//     into LDS (pad 65 -> conflict-free both directions)
//   - each wave splats 16 pixels: lane = channel, 64 consecutive-float
//     atomics per pixel => 2-4 cache lines instead of 65 scattered lines.
__global__ __launch_bounds__(256) void scatter_t_k(
    const float* __restrict__ fmap,    // (B, C, HW)
    const float* __restrict__ flow,    // (B, 2, HW)
    const float* __restrict__ depth,   // (B, 1, HW)
    float* __restrict__ facc_t,        // (B, HW, C) accumulator
    float* __restrict__ wacc)          // (B, HW) weight accumulator
{
    __shared__ float tile[64][65];     // [pixel][channel], padded
    __shared__ int   idx_s[64];
    __shared__ float w_s[64];

    const int t    = threadIdx.x;
    const int lane = t & 63;
    const int wv   = t >> 6;
    const int p0   = blockIdx.x * 64;
    const int b    = blockIdx.y;

    if (t < 64) {
        const int p = p0 + t;
        const float fx = flow[((long)b * 2 + 0) * HWc + p];
        const float fy = flow[((long)b * 2 + 1) * HWc + p];
        const float tx = (float)(p % Wc) + fx;
        const float ty = (float)(p / Wc) + fy;
        int   id = -1;
        float w  = 0.f;
        if (tx >= 0.f && tx < (float)(Wc - 1) && ty >= 0.f && ty < (float)(Hc - 1)) {
            id = (int)ty * Wc + (int)tx;   // trunc == floor (coords >= 0)
            w  = __expf(-depth[(long)b * HWc + p]);
            unsafeAtomicAdd(wacc + (long)b * HWc + id, w);
        }
        idx_s[t] = id;
        w_s[t]   = w;
    }

    // Coalesced fmap tile load: each wave reads 64 consecutive pixels of one
    // channel (256B burst); store transposed into LDS.
    {
        const float* src = fmap + (long)b * Cc * HWc + p0 + lane;
#pragma unroll
        for (int i = 0; i < 16; ++i) {
            const int c = i * 4 + wv;
            tile[lane][c] = src[(long)c * HWc];
        }
    }
    __syncthreads();

    // Wave-wide coalesced atomics: 64 lanes -> 64 consecutive floats.
#pragma unroll
    for (int j = 0; j < 16; ++j) {
        const int q  = wv * 16 + j;
        const int id = idx_s[q];
        if (id >= 0) {
            unsafeAtomicAdd(facc_t + ((long)b * HWc + id) * 64 + lane,
                            tile[q][lane] * w_s[q]);
        }
    }
}

// K2-F: fused normalize + transpose + mask, all batches in one launch.
//   grid = (HW/64, B), 256 threads.
//   read  (pix, c) as float4 (1KB/wave/instr), scale by 1/w,
//   LDS transpose (pad 65 -> only free 2-way conflicts),
//   write (c, pix) as nontemporal float4 (output never re-read),
//   and fold the 0/1 mask write into the same kernel (exclusive ownership
//   of each (b, pixel-tile) by one block).
__global__ __launch_bounds__(256) void norm_fused_k(
    const float* __restrict__ src_t,   // (B, HW, C)
    float* __restrict__ wacc,          // (B, HW): weights in, mask out
    float* __restrict__ dst)           // (B, C, HW)
{
    __shared__ float tile[64][65];     // [channel][pixel], padded
    __shared__ float inv_s[64];

    const int t  = threadIdx.x;
    const int p0 = blockIdx.x * 64;
    const int b  = blockIdx.y;

    if (t < 64) {
        const float w = wacc[(long)b * HWc + p0 + t];
        inv_s[t] = (w > 0.f) ? (1.f / w) : 1.f;
        wacc[(long)b * HWc + p0 + t] = (w > 0.f) ? 1.f : 0.f;  // fused mask
    }
    __syncthreads();

    const int sub = t >> 4;          // 0..15 (pixel / channel sub-index)
    const int q4  = (t & 15) * 4;    // 0,4,...,60

    // Read side: 16 lanes x 16B = 256B per pixel row, 4 rows per instr.
    const float* srcB = src_t + ((long)b * HWc + p0) * 64;
#pragma unroll
    for (int i = 0; i < 4; ++i) {
        const int pix = i * 16 + sub;
        v4f v = *(const v4f*)(srcB + (long)pix * 64 + q4);
        const float s = inv_s[pix];
        tile[q4 + 0][pix] = v[0] * s;
        tile[q4 + 1][pix] = v[1] * s;
        tile[q4 + 2][pix] = v[2] * s;
        tile[q4 + 3][pix] = v[3] * s;
    }
    __syncthreads();

    // Write side: per channel, 16 lanes x 16B = 256B contiguous.
    float* dstB = dst + (long)b * Cc * HWc + p0;
#pragma unroll
    for (int i = 0; i < 4; ++i) {
        const int c = i * 16 + sub;
        v4f v;
        v[0] = tile[c][q4 + 0];
        v[1] = tile[c][q4 + 1];
        v[2] = tile[c][q4 + 2];
        v[3] = tile[c][q4 + 3];
        __builtin_nontemporal_store(v, (v4f*)(dstB + (long)c * HWc + q4));
    }
}

// ===========================================================================
// FALLBACK PATH kernels (Path B / C) — unchanged, correctness safety net
// ===========================================================================

__global__ __launch_bounds__(256) void norm_t_k(
    const float* __restrict__ src_t,   // (HW, C) batch accumulator
    const float* __restrict__ wb,      // (HW) batch weights
    float* __restrict__ dst)           // (C, HW) final batch features
{
    __shared__ float tile[64][65];
    __shared__ float w_s[64];

    const int t    = threadIdx.x;
    const int lane = t & 63;
    const int wv   = t >> 6;
    const int p0   = blockIdx.x * 64;

    if (t < 64) {
        const float w = wb[p0 + t];
        w_s[t] = (w > 0.f) ? (1.f / w) : 1.f;
    }
    __syncthreads();

#pragma unroll
    for (int i = 0; i < 16; ++i) {
        const int pix = i * 4 + wv;
        tile[lane][pix] = src_t[(long)(p0 + pix) * 64 + lane] * w_s[pix];
    }
    __syncthreads();

#pragma unroll
    for (int i = 0; i < 16; ++i) {
        const int c = i * 4 + wv;
        dst[(long)c * HWc + p0 + lane] = tile[c][lane];
    }
}

__global__ __launch_bounds__(256) void mask_k(float* __restrict__ wacc)
{
    const int i = blockIdx.x * 256 + threadIdx.x;   // float4 index
    float4 w = *(float4*)(wacc + (long)i * 4);
    w.x = (w.x > 0.f) ? 1.f : 0.f;
    w.y = (w.y > 0.f) ? 1.f : 0.f;
    w.z = (w.z > 0.f) ? 1.f : 0.f;
    w.w = (w.w > 0.f) ? 1.f : 0.f;
    *(float4*)(wacc + (long)i * 4) = w;
}

__global__ __launch_bounds__(256) void scatter_k(
    const float* __restrict__ fmap,
    const float* __restrict__ flow,
    const float* __restrict__ depth,
    float* __restrict__ facc,
    float* __restrict__ wacc)
{
    const int p = blockIdx.x * 256 + threadIdx.x;
    const int b = blockIdx.y;

    const float fx = flow[((long)b * 2 + 0) * HWc + p];
    const float fy = flow[((long)b * 2 + 1) * HWc + p];
    const int x = p % Wc;
    const int y = p / Wc;
    const float tx = (float)x + fx;
    const float ty = (float)y + fy;

    if (!(tx >= 0.f && tx < (float)(Wc - 1) && ty >= 0.f && ty < (float)(Hc - 1)))
        return;

    const int idx = (int)ty * Wc + (int)tx;
    const float w = __expf(-depth[(long)b * HWc + p]);

    atomicAdd(wacc + (long)b * HWc + idx, w);

    const float* src = fmap + (long)b * Cc * HWc + p;
    float*       dst = facc + (long)b * Cc * HWc + idx;
#pragma unroll
    for (int c = 0; c < Cc; ++c) {
        atomicAdd(dst + (long)c * HWc, src[(long)c * HWc] * w);
    }
}

__global__ __launch_bounds__(256) void norm_k(
    float* __restrict__ facc,
    const float* __restrict__ wacc)
{
    const int bpb = (Cc * HWc) / 1024;
    const int b   = blockIdx.x / bpb;
    const int blk = blockIdx.x % bpb;
    const int e   = blk * 1024 + threadIdx.x * 4;
    const int p   = e % HWc;

    const float4 w4 = *(const float4*)(wacc + (long)b * HWc + p);
    float4 f = *(float4*)(facc + (long)b * (Cc * HWc) + e);
    if (w4.x > 0.f) f.x /= w4.x;
    if (w4.y > 0.f) f.y /= w4.y;
    if (w4.z > 0.f) f.z /= w4.z;
    if (w4.w > 0.f) f.w /= w4.w;
    *(float4*)(facc + (long)b * (Cc * HWc) + e) = f;
}

// ===========================================================================

extern "C" void kernel_launch(void* const* d_in, const int* in_sizes, int n_in,
                              void* d_out, int out_size, void* d_ws, size_t ws_size,
                              hipStream_t stream)
{
    const float* fmap  = (const float*)d_in[0];   // (B,C,H,W)
    const float* flow  = (const float*)d_in[1];   // (B,2,H,W)
    const float* depth = (const float*)d_in[2];   // (B,1,H,W)

    float* out  = (float*)d_out;
    float* facc = out;            // final features: B*C*HW floats
    float* wacc = out + FEATc;    // weight accumulator -> becomes mask

    const size_t featBytes  = (size_t)FEATc * sizeof(float);        // ~302 MB
    const size_t batchBytes = (size_t)Cc * HWc * sizeof(float);     // ~75.5 MB

    if (ws_size >= featBytes) {
        // ---- Path A: transposed accumulator lives in workspace ----
        float* facc_t = (float*)d_ws;
        hipMemsetAsync(d_ws, 0, featBytes, stream);
        hipMemsetAsync(wacc, 0, (size_t)Bc * HWc * sizeof(float), stream);

        dim3 g1(HWc / 64, Bc);
        scatter_t_k<<<g1, 256, 0, stream>>>(fmap, flow, depth, facc_t, wacc);

        dim3 g2(HWc / 64, Bc);
        norm_fused_k<<<g2, 256, 0, stream>>>(facc_t, wacc, facc);
        // mask folded into norm_fused_k — no mask_k pass
    } else if (ws_size >= batchBytes) {
        // ---- Path B: transposed accumulator in d_out, per-batch staging ----
        float* facc_t = out;
        hipMemsetAsync(d_out, 0, (size_t)out_size * sizeof(float), stream);

        dim3 g1(HWc / 64, Bc);
        scatter_t_k<<<g1, 256, 0, stream>>>(fmap, flow, depth, facc_t, wacc);

        for (int b = 0; b < Bc; ++b) {
            hipMemcpyAsync(d_ws, facc_t + (long)b * HWc * 64, batchBytes,
                           hipMemcpyDeviceToDevice, stream);
            norm_t_k<<<HWc / 64, 256, 0, stream>>>(
                (const float*)d_ws,
                wacc + (long)b * HWc,
                facc + (long)b * Cc * HWc);
        }
        mask_k<<<(Bc * HWc) / 1024, 256, 0, stream>>>(wacc);
    } else {
        // ---- Path C: original verified version ----
        hipMemsetAsync(d_out, 0, (size_t)out_size * sizeof(float), stream);

        dim3 g1(HWc / 256, Bc);
        scatter_k<<<g1, 256, 0, stream>>>(fmap, flow, depth, facc, wacc);

        const int norm_blocks = (int)(FEATc / 1024);
        norm_k<<<norm_blocks, 256, 0, stream>>>(facc, wacc);

        const int mask_blocks = (Bc * HWc) / 1024;
        mask_k<<<mask_blocks, 256, 0, stream>>>(wacc);
    }
}

// Round 4
// 777.692 us; speedup vs baseline: 4.4243x; 1.0197x over previous
//
#include <hip/hip_runtime.h>

// Problem constants (from reference): B=4, C=64, H=384, W=768
#define Bc  4
#define Cc  64
#define Hc  384
#define Wc  768
#define HWc (Hc * Wc)                 // 294912
#define FEATc ((long)Bc * Cc * HWc)   // 75497472

typedef float v4f __attribute__((ext_vector_type(4)));

// ===========================================================================
// FAST PATH (transposed accumulator, channel-contiguous atomics)
// ===========================================================================

// K0: zero the transposed accumulator + weight accumulator in one kernel.
// Regular (cacheable) stores on purpose: the zeroed lines should be resident
// in L2/LLC so the scatter's first atomics hit cache, not HBM.
__global__ __launch_bounds__(256) void zero_k(
    float* __restrict__ facc_t,        // FEATc floats
    float* __restrict__ wacc)          // Bc*HWc floats
{
    const int n1 = (int)(FEATc / 4);              // 18,874,368 float4 (fits int)
    const int n2 = (Bc * HWc) / 4;                //    294,912 float4
    const int stride = gridDim.x * 256;
    const v4f z = {0.f, 0.f, 0.f, 0.f};

    for (int i = blockIdx.x * 256 + threadIdx.x; i < n1; i += stride)
        ((v4f*)facc_t)[i] = z;
    for (int i = blockIdx.x * 256 + threadIdx.x; i < n2; i += stride)
        ((v4f*)wacc)[i] = z;
}

// K1-T: scatter splat with (B, HW, C) accumulator layout.
// Block = 256 threads (4 waves) handles 64 source pixels.
//   - threads 0..63 compute idx/w for the 64 pixels (+1 wacc atomic each)
//   - all threads cooperatively load the 64ch x 64pix fmap tile, transposed
//     into LDS (pad 65 -> conflict-free both directions)
//   - each wave splats 16 pixels: lane = channel, 64 consecutive-float
//     atomics per pixel => 2-4 cache lines instead of 65 scattered lines.
// fmap reads are NONTEMPORAL: use-once stream, keep LLC for the accumulator.
__global__ __launch_bounds__(256) void scatter_t_k(
    const float* __restrict__ fmap,    // (B, C, HW)
    const float* __restrict__ flow,    // (B, 2, HW)
    const float* __restrict__ depth,   // (B, 1, HW)
    float* __restrict__ facc_t,        // (B, HW, C) accumulator
    float* __restrict__ wacc)          // (B, HW) weight accumulator
{
    __shared__ float tile[64][65];     // [pixel][channel], padded
    __shared__ int   idx_s[64];
    __shared__ float w_s[64];

    const int t    = threadIdx.x;
    const int lane = t & 63;
    const int wv   = t >> 6;
    const int p0   = blockIdx.x * 64;
    const int b    = blockIdx.y;

    if (t < 64) {
        const int p = p0 + t;
        const float fx = flow[((long)b * 2 + 0) * HWc + p];
        const float fy = flow[((long)b * 2 + 1) * HWc + p];
        const float tx = (float)(p % Wc) + fx;
        const float ty = (float)(p / Wc) + fy;
        int   id = -1;
        float w  = 0.f;
        if (tx >= 0.f && tx < (float)(Wc - 1) && ty >= 0.f && ty < (float)(Hc - 1)) {
            id = (int)ty * Wc + (int)tx;   // trunc == floor (coords >= 0)
            w  = __expf(-depth[(long)b * HWc + p]);
            unsafeAtomicAdd(wacc + (long)b * HWc + id, w);
        }
        idx_s[t] = id;
        w_s[t]   = w;
    }

    // Coalesced fmap tile load (nontemporal): each wave reads 64 consecutive
    // pixels of one channel (256B burst); store transposed into LDS.
    {
        const float* src = fmap + (long)b * Cc * HWc + p0 + lane;
#pragma unroll
        for (int i = 0; i < 16; ++i) {
            const int c = i * 4 + wv;
            tile[lane][c] = __builtin_nontemporal_load(src + (long)c * HWc);
        }
    }
    __syncthreads();

    // Wave-wide coalesced atomics: 64 lanes -> 64 consecutive floats.
#pragma unroll
    for (int j = 0; j < 16; ++j) {
        const int q  = wv * 16 + j;
        const int id = idx_s[q];
        if (id >= 0) {
            unsafeAtomicAdd(facc_t + ((long)b * HWc + id) * 64 + lane,
                            tile[q][lane] * w_s[q]);
        }
    }
}

// K2-F: fused normalize + transpose + mask, all batches in one launch.
//   grid = (HW/64, B), 256 threads.
//   read  (pix, c) as nontemporal float4 (accumulator is dead after this),
//   scale by 1/w, LDS transpose (pad 65 -> only free 2-way conflicts),
//   write (c, pix) as nontemporal float4 (output never re-read),
//   and fold the 0/1 mask write into the same kernel.
__global__ __launch_bounds__(256) void norm_fused_k(
    const float* __restrict__ src_t,   // (B, HW, C)
    float* __restrict__ wacc,          // (B, HW): weights in, mask out
    float* __restrict__ dst)           // (B, C, HW)
{
    __shared__ float tile[64][65];     // [channel][pixel], padded
    __shared__ float inv_s[64];

    const int t  = threadIdx.x;
    const int p0 = blockIdx.x * 64;
    const int b  = blockIdx.y;

    if (t < 64) {
        const float w = wacc[(long)b * HWc + p0 + t];
        inv_s[t] = (w > 0.f) ? (1.f / w) : 1.f;
        wacc[(long)b * HWc + p0 + t] = (w > 0.f) ? 1.f : 0.f;  // fused mask
    }
    __syncthreads();

    const int sub = t >> 4;          // 0..15 (pixel / channel sub-index)
    const int q4  = (t & 15) * 4;    // 0,4,...,60

    // Read side: 16 lanes x 16B = 256B per pixel row, one wave = 1KB burst.
    const float* srcB = src_t + ((long)b * HWc + p0) * 64;
#pragma unroll
    for (int i = 0; i < 4; ++i) {
        const int pix = i * 16 + sub;
        v4f v = __builtin_nontemporal_load((const v4f*)(srcB + (long)pix * 64 + q4));
        const float s = inv_s[pix];
        tile[q4 + 0][pix] = v[0] * s;
        tile[q4 + 1][pix] = v[1] * s;
        tile[q4 + 2][pix] = v[2] * s;
        tile[q4 + 3][pix] = v[3] * s;
    }
    __syncthreads();

    // Write side: per channel, 16 lanes x 16B = 256B contiguous.
    float* dstB = dst + (long)b * Cc * HWc + p0;
#pragma unroll
    for (int i = 0; i < 4; ++i) {
        const int c = i * 16 + sub;
        v4f v;
        v[0] = tile[c][q4 + 0];
        v[1] = tile[c][q4 + 1];
        v[2] = tile[c][q4 + 2];
        v[3] = tile[c][q4 + 3];
        __builtin_nontemporal_store(v, (v4f*)(dstB + (long)c * HWc + q4));
    }
}

// ===========================================================================
// FALLBACK PATH kernels (Path B / C) — unchanged, correctness safety net
// ===========================================================================

__global__ __launch_bounds__(256) void norm_t_k(
    const float* __restrict__ src_t,   // (HW, C) batch accumulator
    const float* __restrict__ wb,      // (HW) batch weights
    float* __restrict__ dst)           // (C, HW) final batch features
{
    __shared__ float tile[64][65];
    __shared__ float w_s[64];

    const int t    = threadIdx.x;
    const int lane = t & 63;
    const int wv   = t >> 6;
    const int p0   = blockIdx.x * 64;

    if (t < 64) {
        const float w = wb[p0 + t];
        w_s[t] = (w > 0.f) ? (1.f / w) : 1.f;
    }
    __syncthreads();

#pragma unroll
    for (int i = 0; i < 16; ++i) {
        const int pix = i * 4 + wv;
        tile[lane][pix] = src_t[(long)(p0 + pix) * 64 + lane] * w_s[pix];
    }
    __syncthreads();

#pragma unroll
    for (int i = 0; i < 16; ++i) {
        const int c = i * 4 + wv;
        dst[(long)c * HWc + p0 + lane] = tile[c][lane];
    }
}

__global__ __launch_bounds__(256) void mask_k(float* __restrict__ wacc)
{
    const int i = blockIdx.x * 256 + threadIdx.x;   // float4 index
    float4 w = *(float4*)(wacc + (long)i * 4);
    w.x = (w.x > 0.f) ? 1.f : 0.f;
    w.y = (w.y > 0.f) ? 1.f : 0.f;
    w.z = (w.z > 0.f) ? 1.f : 0.f;
    w.w = (w.w > 0.f) ? 1.f : 0.f;
    *(float4*)(wacc + (long)i * 4) = w;
}

__global__ __launch_bounds__(256) void scatter_k(
    const float* __restrict__ fmap,
    const float* __restrict__ flow,
    const float* __restrict__ depth,
    float* __restrict__ facc,
    float* __restrict__ wacc)
{
    const int p = blockIdx.x * 256 + threadIdx.x;
    const int b = blockIdx.y;

    const float fx = flow[((long)b * 2 + 0) * HWc + p];
    const float fy = flow[((long)b * 2 + 1) * HWc + p];
    const int x = p % Wc;
    const int y = p / Wc;
    const float tx = (float)x + fx;
    const float ty = (float)y + fy;

    if (!(tx >= 0.f && tx < (float)(Wc - 1) && ty >= 0.f && ty < (float)(Hc - 1)))
        return;

    const int idx = (int)ty * Wc + (int)tx;
    const float w = __expf(-depth[(long)b * HWc + p]);

    atomicAdd(wacc + (long)b * HWc + idx, w);

    const float* src = fmap + (long)b * Cc * HWc + p;
    float*       dst = facc + (long)b * Cc * HWc + idx;
#pragma unroll
    for (int c = 0; c < Cc; ++c) {
        atomicAdd(dst + (long)c * HWc, src[(long)c * HWc] * w);
    }
}

__global__ __launch_bounds__(256) void norm_k(
    float* __restrict__ facc,
    const float* __restrict__ wacc)
{
    const int bpb = (Cc * HWc) / 1024;
    const int b   = blockIdx.x / bpb;
    const int blk = blockIdx.x % bpb;
    const int e   = blk * 1024 + threadIdx.x * 4;
    const int p   = e % HWc;

    const float4 w4 = *(const float4*)(wacc + (long)b * HWc + p);
    float4 f = *(float4*)(facc + (long)b * (Cc * HWc) + e);
    if (w4.x > 0.f) f.x /= w4.x;
    if (w4.y > 0.f) f.y /= w4.y;
    if (w4.z > 0.f) f.z /= w4.z;
    if (w4.w > 0.f) f.w /= w4.w;
    *(float4*)(facc + (long)b * (Cc * HWc) + e) = f;
}

// ===========================================================================

extern "C" void kernel_launch(void* const* d_in, const int* in_sizes, int n_in,
                              void* d_out, int out_size, void* d_ws, size_t ws_size,
                              hipStream_t stream)
{
    const float* fmap  = (const float*)d_in[0];   // (B,C,H,W)
    const float* flow  = (const float*)d_in[1];   // (B,2,H,W)
    const float* depth = (const float*)d_in[2];   // (B,1,H,W)

    float* out  = (float*)d_out;
    float* facc = out;            // final features: B*C*HW floats
    float* wacc = out + FEATc;    // weight accumulator -> becomes mask

    const size_t featBytes  = (size_t)FEATc * sizeof(float);        // ~302 MB
    const size_t batchBytes = (size_t)Cc * HWc * sizeof(float);     // ~75.5 MB

    if (ws_size >= featBytes) {
        // ---- Path A: transposed accumulator lives in workspace ----
        float* facc_t = (float*)d_ws;

        zero_k<<<1024, 256, 0, stream>>>(facc_t, wacc);

        dim3 g1(HWc / 64, Bc);
        scatter_t_k<<<g1, 256, 0, stream>>>(fmap, flow, depth, facc_t, wacc);

        dim3 g2(HWc / 64, Bc);
        norm_fused_k<<<g2, 256, 0, stream>>>(facc_t, wacc, facc);
        // mask folded into norm_fused_k — no mask_k pass
    } else if (ws_size >= batchBytes) {
        // ---- Path B: transposed accumulator in d_out, per-batch staging ----
        float* facc_t = out;
        hipMemsetAsync(d_out, 0, (size_t)out_size * sizeof(float), stream);

        dim3 g1(HWc / 64, Bc);
        scatter_t_k<<<g1, 256, 0, stream>>>(fmap, flow, depth, facc_t, wacc);

        for (int b = 0; b < Bc; ++b) {
            hipMemcpyAsync(d_ws, facc_t + (long)b * HWc * 64, batchBytes,
                           hipMemcpyDeviceToDevice, stream);
            norm_t_k<<<HWc / 64, 256, 0, stream>>>(
                (const float*)d_ws,
                wacc + (long)b * HWc,
                facc + (long)b * Cc * HWc);
        }
        mask_k<<<(Bc * HWc) / 1024, 256, 0, stream>>>(wacc);
    } else {
        // ---- Path C: original verified version ----
        hipMemsetAsync(d_out, 0, (size_t)out_size * sizeof(float), stream);

        dim3 g1(HWc / 256, Bc);
        scatter_k<<<g1, 256, 0, stream>>>(fmap, flow, depth, facc, wacc);

        const int norm_blocks = (int)(FEATc / 1024);
        norm_k<<<norm_blocks, 256, 0, stream>>>(facc, wacc);

        const int mask_blocks = (Bc * HWc) / 1024;
        mask_k<<<mask_blocks, 256, 0, stream>>>(wacc);
    }
}